// Round 1
// baseline (333.197 us; speedup 1.0000x reference)
//
#include <hip/hip_runtime.h>
#include <hip/hip_bf16.h>
#include <stdint.h>

typedef float f32x4 __attribute__((ext_vector_type(4)));
typedef __bf16 bf16x8 __attribute__((ext_vector_type(8)));

#define D_MODEL 1024
#define NHEAD 16
#define DHEAD 64
#define BATCH 2
#define SEQ 2048
#define MROWS (BATCH*SEQ)   // 4096
#define N3 (3*D_MODEL)      // 3072

__device__ __forceinline__ unsigned short f2bf(float f) {
  unsigned int u = __float_as_uint(f);
  u += 0x7FFF + ((u >> 16) & 1);
  return (unsigned short)(u >> 16);
}

// ---------------- fp32 -> bf16 straight convert (x) ----------------
__global__ __launch_bounds__(256) void cvt_f32_bf16(const float* __restrict__ in,
                                                    unsigned short* __restrict__ out, int n4) {
  int i = blockIdx.x*blockDim.x + threadIdx.x;
  int stride = gridDim.x*blockDim.x;
  for (; i < n4; i += stride) {
    float4 f = ((const float4*)in)[i];
    ushort4 u;
    u.x = f2bf(f.x); u.y = f2bf(f.y); u.z = f2bf(f.z); u.w = f2bf(f.w);
    ((ushort4*)out)[i] = u;
  }
}

// ------------- fp32 [K][N] -> bf16 [N][K] transpose-convert -------------
__global__ __launch_bounds__(256) void transpose_cvt(const float* __restrict__ in,
                                                     unsigned short* __restrict__ out,
                                                     int K, int N) {
  __shared__ float tile[32][33];
  int tx = threadIdx.x & 31, ty = threadIdx.x >> 5;  // ty 0..7
  int n0 = blockIdx.x*32, k0 = blockIdx.y*32;
#pragma unroll
  for (int i = 0; i < 4; ++i)
    tile[ty + 8*i][tx] = in[(size_t)(k0 + ty + 8*i)*N + n0 + tx];
  __syncthreads();
#pragma unroll
  for (int i = 0; i < 4; ++i)
    out[(size_t)(n0 + ty + 8*i)*K + k0 + tx] = f2bf(tile[tx][ty + 8*i]);
}

// ---------------- bf16 GEMM: C[M,N] = A[M,K] * Bt[N,K]^T + bias ----------------
#define BM 128
#define BN 128
#define BK 64
#define LDT 72   // padded LDS row stride (ushorts)

__global__ __launch_bounds__(256, 2) void gemm_bt(
    const unsigned short* __restrict__ A,
    const unsigned short* __restrict__ Bt,
    const float* __restrict__ bias,
    int K, int N, int mode,
    unsigned short* __restrict__ qo,
    unsigned short* __restrict__ ko,
    unsigned short* __restrict__ vo,
    float* __restrict__ fo)
{
  __shared__ unsigned short a_lds[BM*LDT];
  __shared__ unsigned short b_lds[BN*LDT];
  int tid = threadIdx.x;
  int lane = tid & 63, wid = tid >> 6;
  int wr = wid >> 1, wc = wid & 1;
  int lr = lane & 15, lh = lane >> 4;
  int M0 = blockIdx.y*BM, N0 = blockIdx.x*BN;

  int srow = tid >> 3;        // 0..31 (+32*i)
  int scol = (tid & 7)*8;     // element col within BK
  const unsigned short* aP = A  + (size_t)(M0 + srow)*K + scol;
  const unsigned short* bP = Bt + (size_t)(N0 + srow)*K + scol;

  int KT = K/BK;
  int4 av[4], bv[4];
#pragma unroll
  for (int i = 0; i < 4; ++i) {
    av[i] = *(const int4*)(aP + (size_t)32*i*K);
    bv[i] = *(const int4*)(bP + (size_t)32*i*K);
  }

  f32x4 acc[4][4];
#pragma unroll
  for (int i = 0; i < 4; ++i)
#pragma unroll
    for (int j = 0; j < 4; ++j) acc[i][j] = (f32x4){0.f, 0.f, 0.f, 0.f};

  for (int kt = 0; kt < KT; ++kt) {
#pragma unroll
    for (int i = 0; i < 4; ++i) {
      *(int4*)&a_lds[(srow + 32*i)*LDT + scol] = av[i];
      *(int4*)&b_lds[(srow + 32*i)*LDT + scol] = bv[i];
    }
    __syncthreads();
    if (kt + 1 < KT) {
      const unsigned short* ap2 = aP + (kt+1)*BK;
      const unsigned short* bp2 = bP + (kt+1)*BK;
#pragma unroll
      for (int i = 0; i < 4; ++i) {
        av[i] = *(const int4*)(ap2 + (size_t)32*i*K);
        bv[i] = *(const int4*)(bp2 + (size_t)32*i*K);
      }
    }
#pragma unroll
    for (int ks = 0; ks < 2; ++ks) {
      bf16x8 af[4], bf[4];
#pragma unroll
      for (int mi = 0; mi < 4; ++mi)
        af[mi] = *(const bf16x8*)&a_lds[(wr*64 + mi*16 + lr)*LDT + ks*32 + lh*8];
#pragma unroll
      for (int ni = 0; ni < 4; ++ni)
        bf[ni] = *(const bf16x8*)&b_lds[(wc*64 + ni*16 + lr)*LDT + ks*32 + lh*8];
#pragma unroll
      for (int mi = 0; mi < 4; ++mi)
#pragma unroll
        for (int ni = 0; ni < 4; ++ni)
          acc[mi][ni] = __builtin_amdgcn_mfma_f32_16x16x32_bf16(af[mi], bf[ni], acc[mi][ni], 0, 0, 0);
    }
    __syncthreads();
  }

  // epilogue
#pragma unroll
  for (int mi = 0; mi < 4; ++mi) {
#pragma unroll
    for (int ni = 0; ni < 4; ++ni) {
      int ncol = N0 + wc*64 + ni*16 + lr;
      float bs = bias[ncol];
      int mbase = M0 + wr*64 + mi*16 + lh*4;
      if (mode == 0) {
        if (ncol < D_MODEL) {
          int h = ncol >> 6, d = ncol & 63;
#pragma unroll
          for (int r = 0; r < 4; ++r) {
            int mrow = mbase + r;
            int b = mrow >> 11, t = mrow & (SEQ-1);
            qo[(((size_t)(b*NHEAD + h))*SEQ + t)*DHEAD + d] = f2bf(acc[mi][ni][r] + bs);
          }
        } else if (ncol < 2*D_MODEL) {
          int c = ncol - D_MODEL, h = c >> 6, d = c & 63;
#pragma unroll
          for (int r = 0; r < 4; ++r) {
            int mrow = mbase + r;
            int b = mrow >> 11, t = mrow & (SEQ-1);
            ko[(((size_t)(b*NHEAD + h))*SEQ + t)*DHEAD + d] = f2bf(acc[mi][ni][r] + bs);
          }
        } else {
          int c = ncol - 2*D_MODEL, h = c >> 6, d = c & 63;
          int b = mbase >> 11, t = mbase & (SEQ-1);
          ushort4 u;
          u.x = f2bf(acc[mi][ni][0] + bs);
          u.y = f2bf(acc[mi][ni][1] + bs);
          u.z = f2bf(acc[mi][ni][2] + bs);
          u.w = f2bf(acc[mi][ni][3] + bs);
          *(ushort4*)&vo[(((size_t)(b*NHEAD + h))*DHEAD + d)*SEQ + t] = u;
        }
      } else {
#pragma unroll
        for (int r = 0; r < 4; ++r) {
          int mrow = mbase + r;
          fo[(size_t)mrow*N + ncol] = acc[mi][ni][r] + bs;
        }
      }
    }
  }
}

// ---------------- causal flash attention ----------------
#define QT 128
#define KVT 64
#define NQT (SEQ/QT)  // 16

__global__ __launch_bounds__(256, 2) void attn_fwd(
    const unsigned short* __restrict__ q,
    const unsigned short* __restrict__ kk,
    const unsigned short* __restrict__ vt,
    unsigned short* __restrict__ out)
{
  __shared__ __bf16 p_lds[4][32][72];
  int tid = threadIdx.x, lane = tid & 63, wid = tid >> 6;
  int qt = blockIdx.x & (NQT-1), bh = blockIdx.x >> 4;
  int b = bh >> 4, h = bh & 15;
  int wq0 = qt*QT + wid*32;
  int lr = lane & 15, lh = lane >> 4;

  const unsigned short* qb = q  + ((size_t)bh*SEQ)*DHEAD;
  const unsigned short* kb = kk + ((size_t)bh*SEQ)*DHEAD;
  const unsigned short* vb = vt + ((size_t)bh*DHEAD)*SEQ;

  bf16x8 qf[2][2];
#pragma unroll
  for (int mi = 0; mi < 2; ++mi)
#pragma unroll
    for (int ks = 0; ks < 2; ++ks)
      qf[mi][ks] = *(const bf16x8*)(qb + (size_t)(wq0 + mi*16 + lr)*DHEAD + ks*32 + lh*8);

  f32x4 o[2][4];
  float mrow[2][4], lrow[2][4];
#pragma unroll
  for (int mi = 0; mi < 2; ++mi) {
#pragma unroll
    for (int nd = 0; nd < 4; ++nd) o[mi][nd] = (f32x4){0.f, 0.f, 0.f, 0.f};
#pragma unroll
    for (int r = 0; r < 4; ++r) { mrow[mi][r] = -1e30f; lrow[mi][r] = 0.f; }
  }

  int nkv = wq0/KVT + 1;
  for (int kt = 0; kt < nkv; ++kt) {
    int kv0 = kt*KVT;
    f32x4 s[2][4];
#pragma unroll
    for (int mi = 0; mi < 2; ++mi)
#pragma unroll
      for (int ni = 0; ni < 4; ++ni) s[mi][ni] = (f32x4){0.f, 0.f, 0.f, 0.f};

    // S = Q K^T
#pragma unroll
    for (int ni = 0; ni < 4; ++ni) {
      const unsigned short* kp = kb + (size_t)(kv0 + ni*16 + lr)*DHEAD + lh*8;
      bf16x8 kf0 = *(const bf16x8*)(kp);
      bf16x8 kf1 = *(const bf16x8*)(kp + 32);
#pragma unroll
      for (int mi = 0; mi < 2; ++mi) {
        s[mi][ni] = __builtin_amdgcn_mfma_f32_16x16x32_bf16(qf[mi][0], kf0, s[mi][ni], 0, 0, 0);
        s[mi][ni] = __builtin_amdgcn_mfma_f32_16x16x32_bf16(qf[mi][1], kf1, s[mi][ni], 0, 0, 0);
      }
    }

    bool domask = (kt == nkv - 1);
#pragma unroll
    for (int mi = 0; mi < 2; ++mi)
#pragma unroll
      for (int ni = 0; ni < 4; ++ni)
#pragma unroll
        for (int r = 0; r < 4; ++r) {
          float v = s[mi][ni][r] * 0.125f;
          if (domask) {
            int qg = wq0 + mi*16 + lh*4 + r;
            int kg = kv0 + ni*16 + lr;
            if (kg > qg) v = -1e30f;
          }
          s[mi][ni][r] = v;
        }

    // online softmax (rows live in (mi, lh, r); reduce across lr group)
#pragma unroll
    for (int mi = 0; mi < 2; ++mi) {
#pragma unroll
      for (int r = 0; r < 4; ++r) {
        float tm = fmaxf(fmaxf(s[mi][0][r], s[mi][1][r]), fmaxf(s[mi][2][r], s[mi][3][r]));
        tm = fmaxf(tm, __shfl_xor(tm, 1));
        tm = fmaxf(tm, __shfl_xor(tm, 2));
        tm = fmaxf(tm, __shfl_xor(tm, 4));
        tm = fmaxf(tm, __shfl_xor(tm, 8));
        float mn = fmaxf(mrow[mi][r], tm);
        float sf = __expf(mrow[mi][r] - mn);
        mrow[mi][r] = mn;
        float rs = 0.f;
#pragma unroll
        for (int ni = 0; ni < 4; ++ni) {
          float p = __expf(s[mi][ni][r] - mn);
          s[mi][ni][r] = p;
          rs += p;
        }
        rs += __shfl_xor(rs, 1);
        rs += __shfl_xor(rs, 2);
        rs += __shfl_xor(rs, 4);
        rs += __shfl_xor(rs, 8);
        lrow[mi][r] = lrow[mi][r]*sf + rs;
#pragma unroll
        for (int nd = 0; nd < 4; ++nd) o[mi][nd][r] *= sf;
#pragma unroll
        for (int ni = 0; ni < 4; ++ni)
          p_lds[wid][mi*16 + lh*4 + r][ni*16 + lr] = (__bf16)s[mi][ni][r];
      }
    }
    asm volatile("" ::: "memory");

    // O += P V
    bf16x8 pa[2][2];
#pragma unroll
    for (int mi = 0; mi < 2; ++mi)
#pragma unroll
      for (int ks = 0; ks < 2; ++ks)
        pa[mi][ks] = *(const bf16x8*)&p_lds[wid][mi*16 + lr][ks*32 + lh*8];
#pragma unroll
    for (int nd = 0; nd < 4; ++nd) {
      const unsigned short* vp = vb + (size_t)(nd*16 + lr)*SEQ + kv0 + lh*8;
      bf16x8 vf0 = *(const bf16x8*)(vp);
      bf16x8 vf1 = *(const bf16x8*)(vp + 32);
#pragma unroll
      for (int mi = 0; mi < 2; ++mi) {
        o[mi][nd] = __builtin_amdgcn_mfma_f32_16x16x32_bf16(pa[mi][0], vf0, o[mi][nd], 0, 0, 0);
        o[mi][nd] = __builtin_amdgcn_mfma_f32_16x16x32_bf16(pa[mi][1], vf1, o[mi][nd], 0, 0, 0);
      }
    }
    asm volatile("" ::: "memory");
  }

  // epilogue: normalize + store [B,T,H*D]
#pragma unroll
  for (int mi = 0; mi < 2; ++mi)
#pragma unroll
    for (int r = 0; r < 4; ++r) {
      float inv = 1.f / lrow[mi][r];
      int tq = wq0 + mi*16 + lh*4 + r;
      size_t rowoff = ((size_t)(b*SEQ) + tq)*D_MODEL + h*DHEAD;
#pragma unroll
      for (int nd = 0; nd < 4; ++nd)
        out[rowoff + nd*16 + lr] = f2bf(o[mi][nd][r] * inv);
    }
}

// ---------------- launcher ----------------
extern "C" void kernel_launch(void* const* d_in, const int* in_sizes, int n_in,
                              void* d_out, int out_size, void* d_ws, size_t ws_size,
                              hipStream_t stream) {
  const float* x      = (const float*)d_in[0];
  const float* qkv_w  = (const float*)d_in[2];
  const float* qkv_b  = (const float*)d_in[3];
  const float* proj_w = (const float*)d_in[4];
  const float* proj_b = (const float*)d_in[5];

  const size_t MB = 1024*1024;
  if (ws_size < 48*MB) return;
  char* w = (char*)d_ws;
  unsigned short* xb      = (unsigned short*)(w);
  unsigned short* wqkv_t  = (unsigned short*)(w + 8*MB);
  unsigned short* wproj_t = (unsigned short*)(w + 14*MB);
  unsigned short* qbuf    = (unsigned short*)(w + 16*MB);
  unsigned short* kbuf    = (unsigned short*)(w + 24*MB);
  unsigned short* vtbuf   = (unsigned short*)(w + 32*MB);
  unsigned short* aout    = (unsigned short*)(w + 40*MB);

  cvt_f32_bf16<<<2048, 256, 0, stream>>>(x, xb, MROWS*D_MODEL/4);
  transpose_cvt<<<dim3(N3/32, D_MODEL/32), 256, 0, stream>>>(qkv_w, wqkv_t, D_MODEL, N3);
  transpose_cvt<<<dim3(D_MODEL/32, D_MODEL/32), 256, 0, stream>>>(proj_w, wproj_t, D_MODEL, D_MODEL);
  gemm_bt<<<dim3(N3/BN, MROWS/BM), 256, 0, stream>>>(xb, wqkv_t, qkv_b, D_MODEL, N3, 0,
                                                     qbuf, kbuf, vtbuf, nullptr);
  attn_fwd<<<dim3(BATCH*NHEAD*NQT), 256, 0, stream>>>(qbuf, kbuf, vtbuf, aout);
  gemm_bt<<<dim3(D_MODEL/BN, MROWS/BM), 256, 0, stream>>>(aout, wproj_t, proj_b, D_MODEL, D_MODEL, 1,
                                                          nullptr, nullptr, nullptr, (float*)d_out);
}

// Round 2
// 173.792 us; speedup vs baseline: 1.9172x; 1.9172x over previous
//
#include <hip/hip_runtime.h>
#include <hip/hip_bf16.h>
#include <stdint.h>

typedef float f32x4 __attribute__((ext_vector_type(4)));
typedef __bf16 bf16x8 __attribute__((ext_vector_type(8)));

#define D_MODEL 1024
#define NHEAD 16
#define DHEAD 64
#define BATCH 2
#define SEQ 2048
#define MROWS (BATCH*SEQ)   // 4096
#define N3 (3*D_MODEL)      // 3072

__device__ __forceinline__ unsigned short f2bf(float f) {
  unsigned int u = __float_as_uint(f);
  u += 0x7FFF + ((u >> 16) & 1);
  return (unsigned short)(u >> 16);
}

// async global->LDS, 16B per lane. lds ptr must be wave-uniform base.
__device__ __forceinline__ void gload_lds16(const void* g, void* l) {
  __builtin_amdgcn_global_load_lds(
      (const __attribute__((address_space(1))) unsigned int*)g,
      (__attribute__((address_space(3))) unsigned int*)l, 16, 0, 0);
}

// ---------------- fp32 -> bf16 straight convert (x) ----------------
__global__ __launch_bounds__(256) void cvt_f32_bf16(const float* __restrict__ in,
                                                    unsigned short* __restrict__ out, int n4) {
  int i = blockIdx.x*blockDim.x + threadIdx.x;
  int stride = gridDim.x*blockDim.x;
  for (; i < n4; i += stride) {
    float4 f = ((const float4*)in)[i];
    ushort4 u;
    u.x = f2bf(f.x); u.y = f2bf(f.y); u.z = f2bf(f.z); u.w = f2bf(f.w);
    ((ushort4*)out)[i] = u;
  }
}

// ------------- fp32 [K][N] -> bf16 [N][K] transpose-convert -------------
__global__ __launch_bounds__(256) void transpose_cvt(const float* __restrict__ in,
                                                     unsigned short* __restrict__ out,
                                                     int K, int N) {
  __shared__ float tile[32][33];
  int tx = threadIdx.x & 31, ty = threadIdx.x >> 5;  // ty 0..7
  int n0 = blockIdx.x*32, k0 = blockIdx.y*32;
#pragma unroll
  for (int i = 0; i < 4; ++i)
    tile[ty + 8*i][tx] = in[(size_t)(k0 + ty + 8*i)*N + n0 + tx];
  __syncthreads();
#pragma unroll
  for (int i = 0; i < 4; ++i)
    out[(size_t)(n0 + ty + 8*i)*K + k0 + tx] = f2bf(tile[tx][ty + 8*i]);
}

// ---------------- bf16 GEMM: C[M,N] = A[M,K] * Bt[N,K]^T + bias ----------------
// m97 structure: linear [128][64] LDS + global_load_lds width=16.
#define BM 128
#define BN 128
#define BK 64

__global__ __launch_bounds__(256, 2) void gemm_bt(
    const unsigned short* __restrict__ A,
    const unsigned short* __restrict__ Bt,
    const float* __restrict__ bias,
    int K, int N, int mode,
    unsigned short* __restrict__ qo,
    unsigned short* __restrict__ ko,
    unsigned short* __restrict__ vo,
    float* __restrict__ fo)
{
  __shared__ unsigned short a_lds[BM*BK];
  __shared__ unsigned short b_lds[BN*BK];
  int tid = threadIdx.x;
  int lane = tid & 63, wid = tid >> 6;
  int wr = wid >> 1, wc = wid & 1;
  int lr = lane & 15, lh = lane >> 4;
  int M0 = blockIdx.y*BM, N0 = blockIdx.x*BN;

  // staging: thread covers 16B at row tid>>3, col (tid&7)*8 -> LDS byte off tid*16
  int srow = tid >> 3;        // 0..31 (+32*i)
  int scol = (tid & 7)*8;
  const unsigned short* aP = A  + (size_t)(M0 + srow)*K + scol;
  const unsigned short* bP = Bt + (size_t)(N0 + srow)*K + scol;
  char* aL = (char*)a_lds + wid*1024;   // wave-uniform dest base
  char* bL = (char*)b_lds + wid*1024;

  int KT = K/BK;

  f32x4 acc[4][4];
#pragma unroll
  for (int i = 0; i < 4; ++i)
#pragma unroll
    for (int j = 0; j < 4; ++j) acc[i][j] = (f32x4){0.f, 0.f, 0.f, 0.f};

  for (int kt = 0; kt < KT; ++kt) {
    const unsigned short* ap = aP + kt*BK;
    const unsigned short* bp = bP + kt*BK;
#pragma unroll
    for (int i = 0; i < 4; ++i) {
      gload_lds16(ap + (size_t)32*i*K, aL + i*4096);
      gload_lds16(bp + (size_t)32*i*K, bL + i*4096);
    }
    __syncthreads();
#pragma unroll
    for (int ks = 0; ks < 2; ++ks) {
      bf16x8 af[4], bf[4];
#pragma unroll
      for (int mi = 0; mi < 4; ++mi)
        af[mi] = *(const bf16x8*)&a_lds[(wr*64 + mi*16 + lr)*BK + ks*32 + lh*8];
#pragma unroll
      for (int ni = 0; ni < 4; ++ni)
        bf[ni] = *(const bf16x8*)&b_lds[(wc*64 + ni*16 + lr)*BK + ks*32 + lh*8];
#pragma unroll
      for (int mi = 0; mi < 4; ++mi)
#pragma unroll
        for (int ni = 0; ni < 4; ++ni)
          acc[mi][ni] = __builtin_amdgcn_mfma_f32_16x16x32_bf16(af[mi], bf[ni], acc[mi][ni], 0, 0, 0);
    }
    __syncthreads();
  }

  // epilogue
#pragma unroll
  for (int mi = 0; mi < 4; ++mi) {
#pragma unroll
    for (int ni = 0; ni < 4; ++ni) {
      int ncol = N0 + wc*64 + ni*16 + lr;
      float bs = bias[ncol];
      int mbase = M0 + wr*64 + mi*16 + lh*4;
      if (mode == 0) {
        if (ncol < D_MODEL) {
          int h = ncol >> 6, d = ncol & 63;
#pragma unroll
          for (int r = 0; r < 4; ++r) {
            int mrow = mbase + r;
            int b = mrow >> 11, t = mrow & (SEQ-1);
            qo[(((size_t)(b*NHEAD + h))*SEQ + t)*DHEAD + d] = f2bf(acc[mi][ni][r] + bs);
          }
        } else if (ncol < 2*D_MODEL) {
          int c = ncol - D_MODEL, h = c >> 6, d = c & 63;
#pragma unroll
          for (int r = 0; r < 4; ++r) {
            int mrow = mbase + r;
            int b = mrow >> 11, t = mrow & (SEQ-1);
            ko[(((size_t)(b*NHEAD + h))*SEQ + t)*DHEAD + d] = f2bf(acc[mi][ni][r] + bs);
          }
        } else {
          int c = ncol - 2*D_MODEL, h = c >> 6, d = c & 63;
          int b = mbase >> 11, t = mbase & (SEQ-1);
          ushort4 u;
          u.x = f2bf(acc[mi][ni][0] + bs);
          u.y = f2bf(acc[mi][ni][1] + bs);
          u.z = f2bf(acc[mi][ni][2] + bs);
          u.w = f2bf(acc[mi][ni][3] + bs);
          *(ushort4*)&vo[(((size_t)(b*NHEAD + h))*DHEAD + d)*SEQ + t] = u;
        }
      } else {
#pragma unroll
        for (int r = 0; r < 4; ++r) {
          int mrow = mbase + r;
          fo[(size_t)mrow*N + ncol] = acc[mi][ni][r] + bs;
        }
      }
    }
  }
}

// ---------------- causal flash attention ----------------
// 1 wave per block, 32 q-rows per block, heavy q-tiles dispatched first.
#define KVT 64
#define NQT32 (SEQ/32)   // 64

__global__ __launch_bounds__(64) void attn_fwd(
    const unsigned short* __restrict__ q,
    const unsigned short* __restrict__ kk,
    const unsigned short* __restrict__ vt,
    unsigned short* __restrict__ out)
{
  __shared__ __bf16 p_lds[32][72];
  int lane = threadIdx.x;
  int idx = blockIdx.x;
  int qt = (NQT32 - 1) - (idx >> 5);   // heavy tiles first
  int bh = idx & 31;                    // b*NHEAD + h
  int b = bh >> 4, h = bh & 15;
  int wq0 = qt*32;
  int lr = lane & 15, lh = lane >> 4;

  const unsigned short* qb = q  + ((size_t)bh*SEQ)*DHEAD;
  const unsigned short* kb = kk + ((size_t)bh*SEQ)*DHEAD;
  const unsigned short* vb = vt + ((size_t)bh*DHEAD)*SEQ;

  bf16x8 qf[2][2];
#pragma unroll
  for (int mi = 0; mi < 2; ++mi)
#pragma unroll
    for (int ks = 0; ks < 2; ++ks)
      qf[mi][ks] = *(const bf16x8*)(qb + (size_t)(wq0 + mi*16 + lr)*DHEAD + ks*32 + lh*8);

  f32x4 o[2][4];
  float mrow[2][4], lrow[2][4];
#pragma unroll
  for (int mi = 0; mi < 2; ++mi) {
#pragma unroll
    for (int nd = 0; nd < 4; ++nd) o[mi][nd] = (f32x4){0.f, 0.f, 0.f, 0.f};
#pragma unroll
    for (int r = 0; r < 4; ++r) { mrow[mi][r] = -1e30f; lrow[mi][r] = 0.f; }
  }

  int nkv = wq0/KVT + 1;
  for (int kt = 0; kt < nkv; ++kt) {
    int kv0 = kt*KVT;
    f32x4 s[2][4];
#pragma unroll
    for (int mi = 0; mi < 2; ++mi)
#pragma unroll
      for (int ni = 0; ni < 4; ++ni) s[mi][ni] = (f32x4){0.f, 0.f, 0.f, 0.f};

    // S = Q K^T
#pragma unroll
    for (int ni = 0; ni < 4; ++ni) {
      const unsigned short* kp = kb + (size_t)(kv0 + ni*16 + lr)*DHEAD + lh*8;
      bf16x8 kf0 = *(const bf16x8*)(kp);
      bf16x8 kf1 = *(const bf16x8*)(kp + 32);
#pragma unroll
      for (int mi = 0; mi < 2; ++mi) {
        s[mi][ni] = __builtin_amdgcn_mfma_f32_16x16x32_bf16(qf[mi][0], kf0, s[mi][ni], 0, 0, 0);
        s[mi][ni] = __builtin_amdgcn_mfma_f32_16x16x32_bf16(qf[mi][1], kf1, s[mi][ni], 0, 0, 0);
      }
    }

    bool domask = (kt == nkv - 1);
#pragma unroll
    for (int mi = 0; mi < 2; ++mi)
#pragma unroll
      for (int ni = 0; ni < 4; ++ni)
#pragma unroll
        for (int r = 0; r < 4; ++r) {
          float v = s[mi][ni][r] * 0.125f;
          if (domask) {
            int qg = wq0 + mi*16 + lh*4 + r;
            int kg = kv0 + ni*16 + lr;
            if (kg > qg) v = -1e30f;
          }
          s[mi][ni][r] = v;
        }

    // online softmax (rows live in (mi, lh, r); reduce across lr group)
#pragma unroll
    for (int mi = 0; mi < 2; ++mi) {
#pragma unroll
      for (int r = 0; r < 4; ++r) {
        float tm = fmaxf(fmaxf(s[mi][0][r], s[mi][1][r]), fmaxf(s[mi][2][r], s[mi][3][r]));
        tm = fmaxf(tm, __shfl_xor(tm, 1));
        tm = fmaxf(tm, __shfl_xor(tm, 2));
        tm = fmaxf(tm, __shfl_xor(tm, 4));
        tm = fmaxf(tm, __shfl_xor(tm, 8));
        float mn = fmaxf(mrow[mi][r], tm);
        float sf = __expf(mrow[mi][r] - mn);
        mrow[mi][r] = mn;
        float rs = 0.f;
#pragma unroll
        for (int ni = 0; ni < 4; ++ni) {
          float p = __expf(s[mi][ni][r] - mn);
          s[mi][ni][r] = p;
          rs += p;
        }
        rs += __shfl_xor(rs, 1);
        rs += __shfl_xor(rs, 2);
        rs += __shfl_xor(rs, 4);
        rs += __shfl_xor(rs, 8);
        lrow[mi][r] = lrow[mi][r]*sf + rs;
#pragma unroll
        for (int nd = 0; nd < 4; ++nd) o[mi][nd][r] *= sf;
#pragma unroll
        for (int ni = 0; ni < 4; ++ni)
          p_lds[mi*16 + lh*4 + r][ni*16 + lr] = (__bf16)s[mi][ni][r];
      }
    }
    asm volatile("" ::: "memory");

    // O += P V
    bf16x8 pa[2][2];
#pragma unroll
    for (int mi = 0; mi < 2; ++mi)
#pragma unroll
      for (int ks = 0; ks < 2; ++ks)
        pa[mi][ks] = *(const bf16x8*)&p_lds[mi*16 + lr][ks*32 + lh*8];
#pragma unroll
    for (int nd = 0; nd < 4; ++nd) {
      const unsigned short* vp = vb + (size_t)(nd*16 + lr)*SEQ + kv0 + lh*8;
      bf16x8 vf0 = *(const bf16x8*)(vp);
      bf16x8 vf1 = *(const bf16x8*)(vp + 32);
#pragma unroll
      for (int mi = 0; mi < 2; ++mi) {
        o[mi][nd] = __builtin_amdgcn_mfma_f32_16x16x32_bf16(pa[mi][0], vf0, o[mi][nd], 0, 0, 0);
        o[mi][nd] = __builtin_amdgcn_mfma_f32_16x16x32_bf16(pa[mi][1], vf1, o[mi][nd], 0, 0, 0);
      }
    }
    asm volatile("" ::: "memory");
  }

  // epilogue: normalize + store [B,T,H*D]
#pragma unroll
  for (int mi = 0; mi < 2; ++mi)
#pragma unroll
    for (int r = 0; r < 4; ++r) {
      float inv = 1.f / lrow[mi][r];
      int tq = wq0 + mi*16 + lh*4 + r;
      size_t rowoff = ((size_t)(b*SEQ) + tq)*D_MODEL + h*DHEAD;
#pragma unroll
      for (int nd = 0; nd < 4; ++nd)
        out[rowoff + nd*16 + lr] = f2bf(o[mi][nd][r] * inv);
    }
}

// ---------------- launcher ----------------
extern "C" void kernel_launch(void* const* d_in, const int* in_sizes, int n_in,
                              void* d_out, int out_size, void* d_ws, size_t ws_size,
                              hipStream_t stream) {
  const float* x      = (const float*)d_in[0];
  const float* qkv_w  = (const float*)d_in[2];
  const float* qkv_b  = (const float*)d_in[3];
  const float* proj_w = (const float*)d_in[4];
  const float* proj_b = (const float*)d_in[5];

  const size_t MB = 1024*1024;
  if (ws_size < 48*MB) return;
  char* w = (char*)d_ws;
  unsigned short* xb      = (unsigned short*)(w);
  unsigned short* wqkv_t  = (unsigned short*)(w + 8*MB);
  unsigned short* wproj_t = (unsigned short*)(w + 14*MB);
  unsigned short* qbuf    = (unsigned short*)(w + 16*MB);
  unsigned short* kbuf    = (unsigned short*)(w + 24*MB);
  unsigned short* vtbuf   = (unsigned short*)(w + 32*MB);
  unsigned short* aout    = (unsigned short*)(w + 40*MB);

  cvt_f32_bf16<<<2048, 256, 0, stream>>>(x, xb, MROWS*D_MODEL/4);
  transpose_cvt<<<dim3(N3/32, D_MODEL/32), 256, 0, stream>>>(qkv_w, wqkv_t, D_MODEL, N3);
  transpose_cvt<<<dim3(D_MODEL/32, D_MODEL/32), 256, 0, stream>>>(proj_w, wproj_t, D_MODEL, D_MODEL);
  gemm_bt<<<dim3(N3/BN, MROWS/BM), 256, 0, stream>>>(xb, wqkv_t, qkv_b, D_MODEL, N3, 0,
                                                     qbuf, kbuf, vtbuf, nullptr);
  attn_fwd<<<dim3(BATCH*NHEAD*NQT32), 64, 0, stream>>>(qbuf, kbuf, vtbuf, aout);
  gemm_bt<<<dim3(D_MODEL/BN, MROWS/BM), 256, 0, stream>>>(aout, wproj_t, proj_b, D_MODEL, D_MODEL, 1,
                                                          nullptr, nullptr, nullptr, (float*)d_out);
}

// Round 3
// 157.843 us; speedup vs baseline: 2.1109x; 1.1010x over previous
//
#include <hip/hip_runtime.h>
#include <hip/hip_bf16.h>
#include <stdint.h>

typedef float f32x4 __attribute__((ext_vector_type(4)));
typedef __bf16 bf16x8 __attribute__((ext_vector_type(8)));

#define D_MODEL 1024
#define NHEAD 16
#define DHEAD 64
#define BATCH 2
#define SEQ 2048
#define MROWS (BATCH*SEQ)   // 4096
#define N3 (3*D_MODEL)      // 3072

__device__ __forceinline__ unsigned short f2bf(float f) {
  unsigned int u = __float_as_uint(f);
  u += 0x7FFF + ((u >> 16) & 1);
  return (unsigned short)(u >> 16);
}

// async global->LDS, 16B per lane. lds ptr must be wave-uniform base.
__device__ __forceinline__ void gload_lds16(const void* g, void* l) {
  __builtin_amdgcn_global_load_lds(
      (const __attribute__((address_space(1))) unsigned int*)g,
      (__attribute__((address_space(3))) unsigned int*)l, 16, 0, 0);
}

// ---------------- fp32 -> bf16 straight convert (x) ----------------
__global__ __launch_bounds__(256) void cvt_f32_bf16(const float* __restrict__ in,
                                                    unsigned short* __restrict__ out, int n4) {
  int i = blockIdx.x*blockDim.x + threadIdx.x;
  int stride = gridDim.x*blockDim.x;
  for (; i < n4; i += stride) {
    float4 f = ((const float4*)in)[i];
    ushort4 u;
    u.x = f2bf(f.x); u.y = f2bf(f.y); u.z = f2bf(f.z); u.w = f2bf(f.w);
    ((ushort4*)out)[i] = u;
  }
}

// ------------- fp32 [K][N] -> bf16 [N][K] transpose-convert -------------
__global__ __launch_bounds__(256) void transpose_cvt(const float* __restrict__ in,
                                                     unsigned short* __restrict__ out,
                                                     int K, int N) {
  __shared__ float tile[32][33];
  int tx = threadIdx.x & 31, ty = threadIdx.x >> 5;  // ty 0..7
  int n0 = blockIdx.x*32, k0 = blockIdx.y*32;
#pragma unroll
  for (int i = 0; i < 4; ++i)
    tile[ty + 8*i][tx] = in[(size_t)(k0 + ty + 8*i)*N + n0 + tx];
  __syncthreads();
#pragma unroll
  for (int i = 0; i < 4; ++i)
    out[(size_t)(n0 + ty + 8*i)*K + k0 + tx] = f2bf(tile[tx][ty + 8*i]);
}

// ---------------- bf16 GEMM: C[M,N] = A[M,K] * Bt[N,K]^T + bias ----------------
// m97 structure: linear [128][64] LDS + global_load_lds width=16.
#define BM 128
#define BN 128
#define BK 64

__global__ __launch_bounds__(256, 2) void gemm_bt(
    const unsigned short* __restrict__ A,
    const unsigned short* __restrict__ Bt,
    const float* __restrict__ bias,
    int K, int N, int mode,
    unsigned short* __restrict__ qo,
    unsigned short* __restrict__ ko,
    unsigned short* __restrict__ vo,
    float* __restrict__ fo)
{
  __shared__ unsigned short a_lds[BM*BK];
  __shared__ unsigned short b_lds[BN*BK];
  int tid = threadIdx.x;
  int lane = tid & 63, wid = tid >> 6;
  int wr = wid >> 1, wc = wid & 1;
  int lr = lane & 15, lh = lane >> 4;
  int M0 = blockIdx.y*BM, N0 = blockIdx.x*BN;

  // staging: thread covers 16B at row tid>>3, col (tid&7)*8 -> LDS byte off tid*16
  int srow = tid >> 3;        // 0..31 (+32*i)
  int scol = (tid & 7)*8;
  const unsigned short* aP = A  + (size_t)(M0 + srow)*K + scol;
  const unsigned short* bP = Bt + (size_t)(N0 + srow)*K + scol;
  char* aL = (char*)a_lds + wid*1024;   // wave-uniform dest base
  char* bL = (char*)b_lds + wid*1024;

  int KT = K/BK;

  f32x4 acc[4][4];
#pragma unroll
  for (int i = 0; i < 4; ++i)
#pragma unroll
    for (int j = 0; j < 4; ++j) acc[i][j] = (f32x4){0.f, 0.f, 0.f, 0.f};

  for (int kt = 0; kt < KT; ++kt) {
    const unsigned short* ap = aP + kt*BK;
    const unsigned short* bp = bP + kt*BK;
#pragma unroll
    for (int i = 0; i < 4; ++i) {
      gload_lds16(ap + (size_t)32*i*K, aL + i*4096);
      gload_lds16(bp + (size_t)32*i*K, bL + i*4096);
    }
    __syncthreads();
#pragma unroll
    for (int ks = 0; ks < 2; ++ks) {
      bf16x8 af[4], bf[4];
#pragma unroll
      for (int mi = 0; mi < 4; ++mi)
        af[mi] = *(const bf16x8*)&a_lds[(wr*64 + mi*16 + lr)*BK + ks*32 + lh*8];
#pragma unroll
      for (int ni = 0; ni < 4; ++ni)
        bf[ni] = *(const bf16x8*)&b_lds[(wc*64 + ni*16 + lr)*BK + ks*32 + lh*8];
#pragma unroll
      for (int mi = 0; mi < 4; ++mi)
#pragma unroll
        for (int ni = 0; ni < 4; ++ni)
          acc[mi][ni] = __builtin_amdgcn_mfma_f32_16x16x32_bf16(af[mi], bf[ni], acc[mi][ni], 0, 0, 0);
    }
    __syncthreads();
  }

  // epilogue
#pragma unroll
  for (int mi = 0; mi < 4; ++mi) {
#pragma unroll
    for (int ni = 0; ni < 4; ++ni) {
      int ncol = N0 + wc*64 + ni*16 + lr;
      float bs = bias[ncol];
      int mbase = M0 + wr*64 + mi*16 + lh*4;
      if (mode == 0) {
        if (ncol < D_MODEL) {
          int h = ncol >> 6, d = ncol & 63;
#pragma unroll
          for (int r = 0; r < 4; ++r) {
            int mrow = mbase + r;
            int b = mrow >> 11, t = mrow & (SEQ-1);
            qo[(((size_t)(b*NHEAD + h))*SEQ + t)*DHEAD + d] = f2bf(acc[mi][ni][r] + bs);
          }
        } else if (ncol < 2*D_MODEL) {
          int c = ncol - D_MODEL, h = c >> 6, d = c & 63;
#pragma unroll
          for (int r = 0; r < 4; ++r) {
            int mrow = mbase + r;
            int b = mrow >> 11, t = mrow & (SEQ-1);
            ko[(((size_t)(b*NHEAD + h))*SEQ + t)*DHEAD + d] = f2bf(acc[mi][ni][r] + bs);
          }
        } else {
          int c = ncol - 2*D_MODEL, h = c >> 6, d = c & 63;
          int b = mbase >> 11, t = mbase & (SEQ-1);
          ushort4 u;
          u.x = f2bf(acc[mi][ni][0] + bs);
          u.y = f2bf(acc[mi][ni][1] + bs);
          u.z = f2bf(acc[mi][ni][2] + bs);
          u.w = f2bf(acc[mi][ni][3] + bs);
          *(ushort4*)&vo[(((size_t)(b*NHEAD + h))*DHEAD + d)*SEQ + t] = u;
        }
      } else {
#pragma unroll
        for (int r = 0; r < 4; ++r) {
          int mrow = mbase + r;
          fo[(size_t)mrow*N + ncol] = acc[mi][ni][r] + bs;
        }
      }
    }
  }
}

// ---------------- causal flash attention ----------------
// Block = 4 waves, all on the SAME 32 q-rows; KV tiles round-robin split
// across waves (intra-block flash-decoding). Partials merged via LDS.
#define KVT 64
#define NQT32 (SEQ/32)   // 64

__global__ __launch_bounds__(256, 4) void attn_fwd(
    const unsigned short* __restrict__ q,
    const unsigned short* __restrict__ kk,
    const unsigned short* __restrict__ vt,
    unsigned short* __restrict__ out)
{
  // union: p_lds [4][32][72]bf16 (18.4KB, loop-only) aliases
  //        o_lds [4][32][64]f32 (32KB) + ml_lds [4][2][32]f32 (1KB, at +32768)
  __shared__ __align__(16) char smem[33792];
  __bf16 (*p_lds)[32][72] = (__bf16 (*)[32][72])smem;
  float  (*o_lds)[32][64] = (float  (*)[32][64])smem;
  float  (*ml_lds)[2][32] = (float  (*)[2][32])(smem + 32768);

  int tid = threadIdx.x, lane = tid & 63, wid = tid >> 6;
  int idx = blockIdx.x;
  int qt = (NQT32 - 1) - (idx >> 5);   // heavy q-tiles first
  int bh = idx & 31;                    // b*NHEAD + h
  int b = bh >> 4, h = bh & 15;
  int wq0 = qt*32;
  int lr = lane & 15, lh = lane >> 4;

  const unsigned short* qb = q  + ((size_t)bh*SEQ)*DHEAD;
  const unsigned short* kb = kk + ((size_t)bh*SEQ)*DHEAD;
  const unsigned short* vb = vt + ((size_t)bh*DHEAD)*SEQ;

  bf16x8 qf[2][2];
#pragma unroll
  for (int mi = 0; mi < 2; ++mi)
#pragma unroll
    for (int ks = 0; ks < 2; ++ks)
      qf[mi][ks] = *(const bf16x8*)(qb + (size_t)(wq0 + mi*16 + lr)*DHEAD + ks*32 + lh*8);

  f32x4 o[2][4];
  float mrow[2][4], lrow[2][4];
#pragma unroll
  for (int mi = 0; mi < 2; ++mi) {
#pragma unroll
    for (int nd = 0; nd < 4; ++nd) o[mi][nd] = (f32x4){0.f, 0.f, 0.f, 0.f};
#pragma unroll
    for (int r = 0; r < 4; ++r) { mrow[mi][r] = -1e30f; lrow[mi][r] = 0.f; }
  }

  int nkv = qt/2 + 1;
  for (int kt = wid; kt < nkv; kt += 4) {
    int kv0 = kt*KVT;
    f32x4 s[2][4];
#pragma unroll
    for (int mi = 0; mi < 2; ++mi)
#pragma unroll
      for (int ni = 0; ni < 4; ++ni) s[mi][ni] = (f32x4){0.f, 0.f, 0.f, 0.f};

    // S = Q K^T
#pragma unroll
    for (int ni = 0; ni < 4; ++ni) {
      const unsigned short* kp = kb + (size_t)(kv0 + ni*16 + lr)*DHEAD + lh*8;
      bf16x8 kf0 = *(const bf16x8*)(kp);
      bf16x8 kf1 = *(const bf16x8*)(kp + 32);
#pragma unroll
      for (int mi = 0; mi < 2; ++mi) {
        s[mi][ni] = __builtin_amdgcn_mfma_f32_16x16x32_bf16(qf[mi][0], kf0, s[mi][ni], 0, 0, 0);
        s[mi][ni] = __builtin_amdgcn_mfma_f32_16x16x32_bf16(qf[mi][1], kf1, s[mi][ni], 0, 0, 0);
      }
    }

    bool domask = (kt == nkv - 1);
#pragma unroll
    for (int mi = 0; mi < 2; ++mi)
#pragma unroll
      for (int ni = 0; ni < 4; ++ni)
#pragma unroll
        for (int r = 0; r < 4; ++r) {
          float v = s[mi][ni][r] * 0.125f;
          if (domask) {
            int qg = wq0 + mi*16 + lh*4 + r;
            int kg = kv0 + ni*16 + lr;
            if (kg > qg) v = -1e30f;
          }
          s[mi][ni][r] = v;
        }

    // online softmax (rows live in (mi, lh, r); reduce across lr group)
#pragma unroll
    for (int mi = 0; mi < 2; ++mi) {
#pragma unroll
      for (int r = 0; r < 4; ++r) {
        float tm = fmaxf(fmaxf(s[mi][0][r], s[mi][1][r]), fmaxf(s[mi][2][r], s[mi][3][r]));
        tm = fmaxf(tm, __shfl_xor(tm, 1));
        tm = fmaxf(tm, __shfl_xor(tm, 2));
        tm = fmaxf(tm, __shfl_xor(tm, 4));
        tm = fmaxf(tm, __shfl_xor(tm, 8));
        float mn = fmaxf(mrow[mi][r], tm);
        float sf = __expf(mrow[mi][r] - mn);
        mrow[mi][r] = mn;
        float rs = 0.f;
#pragma unroll
        for (int ni = 0; ni < 4; ++ni) {
          float p = __expf(s[mi][ni][r] - mn);
          s[mi][ni][r] = p;
          rs += p;
        }
        rs += __shfl_xor(rs, 1);
        rs += __shfl_xor(rs, 2);
        rs += __shfl_xor(rs, 4);
        rs += __shfl_xor(rs, 8);
        lrow[mi][r] = lrow[mi][r]*sf + rs;
#pragma unroll
        for (int nd = 0; nd < 4; ++nd) o[mi][nd][r] *= sf;
#pragma unroll
        for (int ni = 0; ni < 4; ++ni)
          p_lds[wid][mi*16 + lh*4 + r][ni*16 + lr] = (__bf16)s[mi][ni][r];
      }
    }
    asm volatile("" ::: "memory");

    // O += P V
    bf16x8 pa[2][2];
#pragma unroll
    for (int mi = 0; mi < 2; ++mi)
#pragma unroll
      for (int ks = 0; ks < 2; ++ks)
        pa[mi][ks] = *(const bf16x8*)&p_lds[wid][mi*16 + lr][ks*32 + lh*8];
#pragma unroll
    for (int nd = 0; nd < 4; ++nd) {
      const unsigned short* vp = vb + (size_t)(nd*16 + lr)*SEQ + kv0 + lh*8;
      bf16x8 vf0 = *(const bf16x8*)(vp);
      bf16x8 vf1 = *(const bf16x8*)(vp + 32);
#pragma unroll
      for (int mi = 0; mi < 2; ++mi) {
        o[mi][nd] = __builtin_amdgcn_mfma_f32_16x16x32_bf16(pa[mi][0], vf0, o[mi][nd], 0, 0, 0);
        o[mi][nd] = __builtin_amdgcn_mfma_f32_16x16x32_bf16(pa[mi][1], vf1, o[mi][nd], 0, 0, 0);
      }
    }
    asm volatile("" ::: "memory");
  }

  // all waves done with p_lds before aliased o_lds is written
  __syncthreads();

  // stage per-wave partials (unnormalized O, running m and l)
#pragma unroll
  for (int mi = 0; mi < 2; ++mi)
#pragma unroll
    for (int r = 0; r < 4; ++r) {
      int row = mi*16 + lh*4 + r;
      ml_lds[wid][0][row] = mrow[mi][r];   // identical across lr lanes
      ml_lds[wid][1][row] = lrow[mi][r];
#pragma unroll
      for (int nd = 0; nd < 4; ++nd)
        o_lds[wid][row][nd*16 + lr] = o[mi][nd][r];
    }
  __syncthreads();

  // merge 4 partials: thread -> (row = tid>>3, cols cb..cb+7)
  {
    int row = tid >> 3, cb = (tid & 7)*8;
    float M = fmaxf(fmaxf(ml_lds[0][0][row], ml_lds[1][0][row]),
                    fmaxf(ml_lds[2][0][row], ml_lds[3][0][row]));
    float L = 0.f;
    float acc8[8];
#pragma unroll
    for (int c = 0; c < 8; ++c) acc8[c] = 0.f;
#pragma unroll
    for (int w = 0; w < 4; ++w) {
      float sw = __expf(ml_lds[w][0][row] - M);
      L += sw * ml_lds[w][1][row];
      const f32x4* op = (const f32x4*)&o_lds[w][row][cb];
      f32x4 v0 = op[0], v1 = op[1];
#pragma unroll
      for (int c = 0; c < 4; ++c) { acc8[c] += sw*v0[c]; acc8[4+c] += sw*v1[c]; }
    }
    float inv = 1.f / L;
    union { unsigned short us[8]; int4 v; } pk;
#pragma unroll
    for (int c = 0; c < 8; ++c) pk.us[c] = f2bf(acc8[c]*inv);
    int tq = wq0 + row;
    size_t off = ((size_t)(b*SEQ) + tq)*D_MODEL + h*DHEAD + cb;
    *(int4*)(out + off) = pk.v;
  }
}

// ---------------- launcher ----------------
extern "C" void kernel_launch(void* const* d_in, const int* in_sizes, int n_in,
                              void* d_out, int out_size, void* d_ws, size_t ws_size,
                              hipStream_t stream) {
  const float* x      = (const float*)d_in[0];
  const float* qkv_w  = (const float*)d_in[2];
  const float* qkv_b  = (const float*)d_in[3];
  const float* proj_w = (const float*)d_in[4];
  const float* proj_b = (const float*)d_in[5];

  const size_t MB = 1024*1024;
  if (ws_size < 48*MB) return;
  char* w = (char*)d_ws;
  unsigned short* xb      = (unsigned short*)(w);
  unsigned short* wqkv_t  = (unsigned short*)(w + 8*MB);
  unsigned short* wproj_t = (unsigned short*)(w + 14*MB);
  unsigned short* qbuf    = (unsigned short*)(w + 16*MB);
  unsigned short* kbuf    = (unsigned short*)(w + 24*MB);
  unsigned short* vtbuf   = (unsigned short*)(w + 32*MB);
  unsigned short* aout    = (unsigned short*)(w + 40*MB);

  cvt_f32_bf16<<<2048, 256, 0, stream>>>(x, xb, MROWS*D_MODEL/4);
  transpose_cvt<<<dim3(N3/32, D_MODEL/32), 256, 0, stream>>>(qkv_w, wqkv_t, D_MODEL, N3);
  transpose_cvt<<<dim3(D_MODEL/32, D_MODEL/32), 256, 0, stream>>>(proj_w, wproj_t, D_MODEL, D_MODEL);
  gemm_bt<<<dim3(N3/BN, MROWS/BM), 256, 0, stream>>>(xb, wqkv_t, qkv_b, D_MODEL, N3, 0,
                                                     qbuf, kbuf, vtbuf, nullptr);
  attn_fwd<<<dim3(BATCH*NHEAD*NQT32), 256, 0, stream>>>(qbuf, kbuf, vtbuf, aout);
  gemm_bt<<<dim3(D_MODEL/BN, MROWS/BM), 256, 0, stream>>>(aout, wproj_t, proj_b, D_MODEL, D_MODEL, 1,
                                                          nullptr, nullptr, nullptr, (float*)d_out);
}

// Round 4
// 149.272 us; speedup vs baseline: 2.2321x; 1.0574x over previous
//
#include <hip/hip_runtime.h>
#include <hip/hip_bf16.h>
#include <stdint.h>

typedef float f32x4 __attribute__((ext_vector_type(4)));
typedef float f32x16 __attribute__((ext_vector_type(16)));
typedef __bf16 bf16x8 __attribute__((ext_vector_type(8)));
typedef unsigned int uint2v __attribute__((ext_vector_type(2)));

#define D_MODEL 1024
#define NHEAD 16
#define DHEAD 64
#define BATCH 2
#define SEQ 2048
#define MROWS (BATCH*SEQ)   // 4096
#define N3 (3*D_MODEL)      // 3072

// 0.125 (1/sqrt(Dh)) * log2(e): folded into Q so attention uses exp2 directly
#define SCALE_LOG2E 0.1803368801111244f

__device__ __forceinline__ unsigned short f2bf(float f) {
  unsigned int u = __float_as_uint(f);
  u += 0x7FFF + ((u >> 16) & 1);
  return (unsigned short)(u >> 16);
}

// pack two f32 -> one dword of 2 bf16 (elem0 = x in low 16)
#define CVTPK(d, x, y) asm("v_cvt_pk_bf16_f32 %0, %1, %2" : "=v"(d) : "v"(x), "v"(y))
// swap lanes 32-63 of x with lanes 0-31 of y
#define SWAP32(x, y) do { uint2v _r = __builtin_amdgcn_permlane32_swap((x), (y), false, false); \
                          (x) = _r[0]; (y) = _r[1]; } while (0)

// async global->LDS, 16B per lane. lds ptr must be wave-uniform base.
__device__ __forceinline__ void gload_lds16(const void* g, void* l) {
  __builtin_amdgcn_global_load_lds(
      (const __attribute__((address_space(1))) unsigned int*)g,
      (__attribute__((address_space(3))) unsigned int*)l, 16, 0, 0);
}

// ---------------- fp32 -> bf16 straight convert (x) ----------------
__global__ __launch_bounds__(256) void cvt_f32_bf16(const float* __restrict__ in,
                                                    unsigned short* __restrict__ out, int n4) {
  int i = blockIdx.x*blockDim.x + threadIdx.x;
  int stride = gridDim.x*blockDim.x;
  for (; i < n4; i += stride) {
    float4 f = ((const float4*)in)[i];
    ushort4 u;
    u.x = f2bf(f.x); u.y = f2bf(f.y); u.z = f2bf(f.z); u.w = f2bf(f.w);
    ((ushort4*)out)[i] = u;
  }
}

// ------------- fp32 [K][N] -> bf16 [N][K] transpose-convert -------------
__global__ __launch_bounds__(256) void transpose_cvt(const float* __restrict__ in,
                                                     unsigned short* __restrict__ out,
                                                     int K, int N) {
  __shared__ float tile[32][33];
  int tx = threadIdx.x & 31, ty = threadIdx.x >> 5;  // ty 0..7
  int n0 = blockIdx.x*32, k0 = blockIdx.y*32;
#pragma unroll
  for (int i = 0; i < 4; ++i)
    tile[ty + 8*i][tx] = in[(size_t)(k0 + ty + 8*i)*N + n0 + tx];
  __syncthreads();
#pragma unroll
  for (int i = 0; i < 4; ++i)
    out[(size_t)(n0 + ty + 8*i)*K + k0 + tx] = f2bf(tile[tx][ty + 8*i]);
}

// ---------------- bf16 GEMM: C[M,N] = A[M,K] * Bt[N,K]^T + bias ----------------
// m97 structure: linear [128][64] LDS + global_load_lds width=16.
#define BM 128
#define BN 128
#define BK 64

__global__ __launch_bounds__(256, 2) void gemm_bt(
    const unsigned short* __restrict__ A,
    const unsigned short* __restrict__ Bt,
    const float* __restrict__ bias,
    int K, int N, int mode,
    unsigned short* __restrict__ qo,
    unsigned short* __restrict__ ko,
    unsigned short* __restrict__ vo,
    float* __restrict__ fo)
{
  __shared__ unsigned short a_lds[BM*BK];
  __shared__ unsigned short b_lds[BN*BK];
  int tid = threadIdx.x;
  int lane = tid & 63, wid = tid >> 6;
  int wr = wid >> 1, wc = wid & 1;
  int lr = lane & 15, lh = lane >> 4;
  int M0 = blockIdx.y*BM, N0 = blockIdx.x*BN;

  // staging: thread covers 16B at row tid>>3, col (tid&7)*8 -> LDS byte off tid*16
  int srow = tid >> 3;        // 0..31 (+32*i)
  int scol = (tid & 7)*8;
  const unsigned short* aP = A  + (size_t)(M0 + srow)*K + scol;
  const unsigned short* bP = Bt + (size_t)(N0 + srow)*K + scol;
  char* aL = (char*)a_lds + wid*1024;   // wave-uniform dest base
  char* bL = (char*)b_lds + wid*1024;

  int KT = K/BK;

  f32x4 acc[4][4];
#pragma unroll
  for (int i = 0; i < 4; ++i)
#pragma unroll
    for (int j = 0; j < 4; ++j) acc[i][j] = (f32x4){0.f, 0.f, 0.f, 0.f};

  for (int kt = 0; kt < KT; ++kt) {
    const unsigned short* ap = aP + kt*BK;
    const unsigned short* bp = bP + kt*BK;
#pragma unroll
    for (int i = 0; i < 4; ++i) {
      gload_lds16(ap + (size_t)32*i*K, aL + i*4096);
      gload_lds16(bp + (size_t)32*i*K, bL + i*4096);
    }
    __syncthreads();
#pragma unroll
    for (int ks = 0; ks < 2; ++ks) {
      bf16x8 af[4], bf[4];
#pragma unroll
      for (int mi = 0; mi < 4; ++mi)
        af[mi] = *(const bf16x8*)&a_lds[(wr*64 + mi*16 + lr)*BK + ks*32 + lh*8];
#pragma unroll
      for (int ni = 0; ni < 4; ++ni)
        bf[ni] = *(const bf16x8*)&b_lds[(wc*64 + ni*16 + lr)*BK + ks*32 + lh*8];
#pragma unroll
      for (int mi = 0; mi < 4; ++mi)
#pragma unroll
        for (int ni = 0; ni < 4; ++ni)
          acc[mi][ni] = __builtin_amdgcn_mfma_f32_16x16x32_bf16(af[mi], bf[ni], acc[mi][ni], 0, 0, 0);
    }
    __syncthreads();
  }

  // epilogue
#pragma unroll
  for (int mi = 0; mi < 4; ++mi) {
#pragma unroll
    for (int ni = 0; ni < 4; ++ni) {
      int ncol = N0 + wc*64 + ni*16 + lr;
      float bs = bias[ncol];
      int mbase = M0 + wr*64 + mi*16 + lh*4;
      if (mode == 0) {
        if (ncol < D_MODEL) {
          int h = ncol >> 6, d = ncol & 63;
#pragma unroll
          for (int r = 0; r < 4; ++r) {
            int mrow = mbase + r;
            int b = mrow >> 11, t = mrow & (SEQ-1);
            // pre-scale Q by 0.125*log2(e) so attention works in exp2 domain
            qo[(((size_t)(b*NHEAD + h))*SEQ + t)*DHEAD + d] =
                f2bf((acc[mi][ni][r] + bs) * SCALE_LOG2E);
          }
        } else if (ncol < 2*D_MODEL) {
          int c = ncol - D_MODEL, h = c >> 6, d = c & 63;
#pragma unroll
          for (int r = 0; r < 4; ++r) {
            int mrow = mbase + r;
            int b = mrow >> 11, t = mrow & (SEQ-1);
            ko[(((size_t)(b*NHEAD + h))*SEQ + t)*DHEAD + d] = f2bf(acc[mi][ni][r] + bs);
          }
        } else {
          int c = ncol - 2*D_MODEL, h = c >> 6, d = c & 63;
          int b = mbase >> 11, t = mbase & (SEQ-1);
          ushort4 u;
          u.x = f2bf(acc[mi][ni][0] + bs);
          u.y = f2bf(acc[mi][ni][1] + bs);
          u.z = f2bf(acc[mi][ni][2] + bs);
          u.w = f2bf(acc[mi][ni][3] + bs);
          *(ushort4*)&vo[(((size_t)(b*NHEAD + h))*DHEAD + d)*SEQ + t] = u;
        }
      } else {
#pragma unroll
        for (int r = 0; r < 4; ++r) {
          int mrow = mbase + r;
          fo[(size_t)mrow*N + ncol] = acc[mi][ni][r] + bs;
        }
      }
    }
  }
}

// ---------------- causal flash attention (swapped-QK^T, in-register softmax) ----
// Block = 4 waves on the SAME 32 q-rows; KV tiles round-robin across waves.
// S^T = mfma32(K,Q): q = lane&31, k lane-local -> row reduce = in-lane + 1 shfl.
// P redistributed to PV B-fragments via cvt_pk_bf16 + permlane32_swap (no LDS).
// O^T accumulated; partials merged through LDS at the end.
#define KVT 64
#define NQT32 (SEQ/32)   // 64

__global__ __launch_bounds__(256, 3) void attn_fwd(
    const unsigned short* __restrict__ q,
    const unsigned short* __restrict__ kk,
    const unsigned short* __restrict__ vt,
    unsigned short* __restrict__ out)
{
  __shared__ float o_lds[4][32][64];
  __shared__ float ml_lds[4][2][32];

  int tid = threadIdx.x, lane = tid & 63, wid = tid >> 6;
  int idx = blockIdx.x;
  int qt = (NQT32 - 1) - (idx >> 5);   // heavy q-tiles first
  int bh = idx & 31;                    // b*NHEAD + h
  int b = bh >> 4, h = bh & 15;
  int wq0 = qt*32;
  int l31 = lane & 31, hl = lane >> 5;

  const unsigned short* qb = q  + ((size_t)bh*SEQ)*DHEAD;
  const unsigned short* kb = kk + ((size_t)bh*SEQ)*DHEAD;
  const unsigned short* vb = vt + ((size_t)bh*DHEAD)*SEQ;

  // Q fragments (B-operand): lane holds Q[wq0+l31][st*16 + hl*8 .. +7]
  bf16x8 qf[4];
#pragma unroll
  for (int st = 0; st < 4; ++st)
    qf[st] = *(const bf16x8*)(qb + (size_t)(wq0 + l31)*DHEAD + st*16 + hl*8);

  f32x16 o0, o1;   // O^T: d = {0..31, 32..63}, q = l31
#pragma unroll
  for (int i = 0; i < 16; ++i) { o0[i] = 0.f; o1[i] = 0.f; }
  float m = -1e30f, l = 0.f;   // per-q (log2 domain)
  int qg = wq0 + l31;

  int nkv = qt/2 + 1;
  for (int kt = wid; kt < nkv; kt += 4) {
    int kv0 = kt*KVT;
    f32x16 s0, s1;   // S^T: k = kv0 + {0..31, 32..63}, q = l31
#pragma unroll
    for (int i = 0; i < 16; ++i) { s0[i] = 0.f; s1[i] = 0.f; }

    // S^T = K * Q^T  (A = K rows, B = Q rows)
#pragma unroll
    for (int st = 0; st < 4; ++st) {
      bf16x8 kf0 = *(const bf16x8*)(kb + (size_t)(kv0 + l31)*DHEAD + st*16 + hl*8);
      bf16x8 kf1 = *(const bf16x8*)(kb + (size_t)(kv0 + 32 + l31)*DHEAD + st*16 + hl*8);
      s0 = __builtin_amdgcn_mfma_f32_32x32x16_bf16(kf0, qf[st], s0, 0, 0, 0);
      s1 = __builtin_amdgcn_mfma_f32_32x32x16_bf16(kf1, qf[st], s1, 0, 0, 0);
    }

    // causal mask (diagonal tile only); k_local = (r&3)+8*(r>>2)+4*hl
    if (kt == nkv - 1) {
#pragma unroll
      for (int r = 0; r < 16; ++r) {
        int kl = (r&3) + 8*(r>>2) + 4*hl;
        if (kv0 + kl      > qg) s0[r] = -1e30f;
        if (kv0 + 32 + kl > qg) s1[r] = -1e30f;
      }
    }

    // in-lane tile max + combine with partner half-wave
    float tm = s0[0];
#pragma unroll
    for (int r = 1; r < 16; ++r) tm = fmaxf(tm, s0[r]);
#pragma unroll
    for (int r = 0; r < 16; ++r) tm = fmaxf(tm, s1[r]);
    tm = fmaxf(tm, __shfl_xor(tm, 32));

    // defer-max: rescale only when max grows materially (THR = 11 in log2)
    if (!__all(tm <= m + 11.0f)) {
      float mn = fmaxf(m, tm);
      float sf = __builtin_amdgcn_exp2f(m - mn);
      m = mn;
      l *= sf;
      o0 *= sf;
      o1 *= sf;
    }

    // P = exp2(S - m); pack to bf16 pairs and redistribute across half-waves
    float rs = 0.f;
    uint32_t pw[4][4];
    {
      float p[16];
#pragma unroll
      for (int r = 0; r < 16; ++r) { p[r] = __builtin_amdgcn_exp2f(s0[r] - m); rs += p[r]; }
      uint32_t a0,a1,a2,a3,b0,b1,b2,b3;
      CVTPK(a0, p[0],  p[1]);  CVTPK(a1, p[2],  p[3]);
      CVTPK(b0, p[4],  p[5]);  CVTPK(b1, p[6],  p[7]);
      CVTPK(a2, p[8],  p[9]);  CVTPK(a3, p[10], p[11]);
      CVTPK(b2, p[12], p[13]); CVTPK(b3, p[14], p[15]);
      SWAP32(a0, b0); SWAP32(a1, b1); SWAP32(a2, b2); SWAP32(a3, b3);
      pw[0][0]=a0; pw[0][1]=a1; pw[0][2]=b0; pw[0][3]=b1;
      pw[1][0]=a2; pw[1][1]=a3; pw[1][2]=b2; pw[1][3]=b3;
    }
    {
      float p[16];
#pragma unroll
      for (int r = 0; r < 16; ++r) { p[r] = __builtin_amdgcn_exp2f(s1[r] - m); rs += p[r]; }
      uint32_t a0,a1,a2,a3,b0,b1,b2,b3;
      CVTPK(a0, p[0],  p[1]);  CVTPK(a1, p[2],  p[3]);
      CVTPK(b0, p[4],  p[5]);  CVTPK(b1, p[6],  p[7]);
      CVTPK(a2, p[8],  p[9]);  CVTPK(a3, p[10], p[11]);
      CVTPK(b2, p[12], p[13]); CVTPK(b3, p[14], p[15]);
      SWAP32(a0, b0); SWAP32(a1, b1); SWAP32(a2, b2); SWAP32(a3, b3);
      pw[2][0]=a0; pw[2][1]=a1; pw[2][2]=b0; pw[2][3]=b1;
      pw[3][0]=a2; pw[3][1]=a3; pw[3][2]=b2; pw[3][3]=b3;
    }
    rs += __shfl_xor(rs, 32);
    l += rs;

    // O^T += V^T * P^T
#pragma unroll
    for (int st = 0; st < 4; ++st) {
      union { uint32_t u[4]; bf16x8 v; } pf;
      pf.u[0] = pw[st][0]; pf.u[1] = pw[st][1]; pf.u[2] = pw[st][2]; pf.u[3] = pw[st][3];
      bf16x8 vf0 = *(const bf16x8*)(vb + (size_t)(l31)*SEQ      + kv0 + st*16 + hl*8);
      bf16x8 vf1 = *(const bf16x8*)(vb + (size_t)(32 + l31)*SEQ + kv0 + st*16 + hl*8);
      o0 = __builtin_amdgcn_mfma_f32_32x32x16_bf16(vf0, pf.v, o0, 0, 0, 0);
      o1 = __builtin_amdgcn_mfma_f32_32x32x16_bf16(vf1, pf.v, o1, 0, 0, 0);
    }
  }

  // stage per-wave partials: O^T regs -> o_lds[wid][q][d]
  if (hl == 0) { ml_lds[wid][0][l31] = m; ml_lds[wid][1][l31] = l; }
#pragma unroll
  for (int r = 0; r < 16; ++r) {
    int dl = (r&3) + 8*(r>>2) + 4*hl;
    o_lds[wid][l31][dl]      = o0[r];
    o_lds[wid][l31][32 + dl] = o1[r];
  }
  __syncthreads();

  // merge 4 partials: thread -> (row = tid>>3, cols cb..cb+7)
  {
    int row = tid >> 3, cb = (tid & 7)*8;
    float M = fmaxf(fmaxf(ml_lds[0][0][row], ml_lds[1][0][row]),
                    fmaxf(ml_lds[2][0][row], ml_lds[3][0][row]));
    float L = 0.f;
    float acc8[8];
#pragma unroll
    for (int c = 0; c < 8; ++c) acc8[c] = 0.f;
#pragma unroll
    for (int w = 0; w < 4; ++w) {
      float sw = __builtin_amdgcn_exp2f(ml_lds[w][0][row] - M);
      L += sw * ml_lds[w][1][row];
      const f32x4* op = (const f32x4*)&o_lds[w][row][cb];
      f32x4 v0 = op[0], v1 = op[1];
#pragma unroll
      for (int c = 0; c < 4; ++c) { acc8[c] += sw*v0[c]; acc8[4+c] += sw*v1[c]; }
    }
    float inv = 1.f / L;
    union { unsigned short us[8]; int4 v; } pk;
#pragma unroll
    for (int c = 0; c < 8; ++c) pk.us[c] = f2bf(acc8[c]*inv);
    int tq = wq0 + row;
    size_t off = ((size_t)(b*SEQ) + tq)*D_MODEL + h*DHEAD + cb;
    *(int4*)(out + off) = pk.v;
  }
}

// ---------------- launcher ----------------
extern "C" void kernel_launch(void* const* d_in, const int* in_sizes, int n_in,
                              void* d_out, int out_size, void* d_ws, size_t ws_size,
                              hipStream_t stream) {
  const float* x      = (const float*)d_in[0];
  const float* qkv_w  = (const float*)d_in[2];
  const float* qkv_b  = (const float*)d_in[3];
  const float* proj_w = (const float*)d_in[4];
  const float* proj_b = (const float*)d_in[5];

  const size_t MB = 1024*1024;
  if (ws_size < 48*MB) return;
  char* w = (char*)d_ws;
  unsigned short* xb      = (unsigned short*)(w);
  unsigned short* wqkv_t  = (unsigned short*)(w + 8*MB);
  unsigned short* wproj_t = (unsigned short*)(w + 14*MB);
  unsigned short* qbuf    = (unsigned short*)(w + 16*MB);
  unsigned short* kbuf    = (unsigned short*)(w + 24*MB);
  unsigned short* vtbuf   = (unsigned short*)(w + 32*MB);
  unsigned short* aout    = (unsigned short*)(w + 40*MB);

  cvt_f32_bf16<<<2048, 256, 0, stream>>>(x, xb, MROWS*D_MODEL/4);
  transpose_cvt<<<dim3(N3/32, D_MODEL/32), 256, 0, stream>>>(qkv_w, wqkv_t, D_MODEL, N3);
  transpose_cvt<<<dim3(D_MODEL/32, D_MODEL/32), 256, 0, stream>>>(proj_w, wproj_t, D_MODEL, D_MODEL);
  gemm_bt<<<dim3(N3/BN, MROWS/BM), 256, 0, stream>>>(xb, wqkv_t, qkv_b, D_MODEL, N3, 0,
                                                     qbuf, kbuf, vtbuf, nullptr);
  attn_fwd<<<dim3(BATCH*NHEAD*NQT32), 256, 0, stream>>>(qbuf, kbuf, vtbuf, aout);
  gemm_bt<<<dim3(D_MODEL/BN, MROWS/BM), 256, 0, stream>>>(aout, wproj_t, proj_b, D_MODEL, D_MODEL, 1,
                                                          nullptr, nullptr, nullptr, (float*)d_out);
}